// Round 1
// baseline (403.331 us; speedup 1.0000x reference)
//
#include <hip/hip_runtime.h>
#include <hip/hip_bf16.h>

// R-GCN layer (fp32 in/out): out = relu(agg0/deg0 @ W0 + agg1/deg1 @ W1 + x @ Wl + b)
// Round 8: agg rewritten as LDS-staged CSR (single global pass over binned)
// + depth-2 software-pipelined gather (8 gathers in flight per half-wave)
// + nontemporal loads/stores to keep xb L2-resident. zero folded into pack_b,
// hist fused into convert. 8 launches -> 6.
//
// ws: wb ushort[12*8*64*8] | binned uint[2E] | xb bf16[N*128] |
//     aggb bf16[2N*128] | ghist int[NB] | S int[NB+1] | cursor int[NB]
// Requires N <= 131072 (src packed into 17 bits).

#define DFEAT 128
#define CH2 16384        // edges per hist/bin block
#define NBMAX 1600       // max buckets = ceil(2N/128)
#define CAPN 2816        // LDS edge capacity per bucket (mean 2048, sd ~45 -> +17 sigma)

typedef __attribute__((ext_vector_type(8))) short short8v;       // 8 bf16 (4 VGPRs)
typedef __attribute__((ext_vector_type(4))) float float4v;       // 4 fp32
typedef __attribute__((ext_vector_type(2))) unsigned int uint2v; // 8B
typedef __attribute__((ext_vector_type(4))) unsigned short ushort4v;

__device__ __forceinline__ float4v bfexp(uint2v g) {
    // unpack 4 bf16 (packed in 2 dwords) to 4 fp32
    float4v v;
    v[0] = __uint_as_float(g[0] << 16);
    v[1] = __uint_as_float(g[0] & 0xffff0000u);
    v[2] = __uint_as_float(g[1] << 16);
    v[3] = __uint_as_float(g[1] & 0xffff0000u);
    return v;
}

// Pack B[k][col] (k<256: wrel, else wloop) into MFMA B-fragment order; also
// zero ghist (6144 threads >= NB).
__global__ void pack_b_kernel(const float* __restrict__ wrel,
                              const float* __restrict__ wloop,
                              unsigned short* __restrict__ wb,
                              int* __restrict__ ghist, int NB) {
    int t = blockIdx.x * blockDim.x + threadIdx.x;   // 0..6143
    if (t < NB) ghist[t] = 0;
    if (t >= 12 * 8 * 64) return;
    int lane = t & 63;
    int kbase = (t >> 9) * 32 + (lane >> 4) * 8;
    int col = (((t >> 6) & 7) << 4) + (lane & 15);
    unsigned short tmp[8];
#pragma unroll
    for (int j = 0; j < 8; ++j) {
        int k = kbase + j;
        float v = (k < 256) ? wrel[k * DFEAT + col] : wloop[(k - 256) * DFEAT + col];
        tmp[j] = __hip_bfloat16_raw(__float2bfloat16(v)).x;
    }
    *(ushort4*)(wb + t * 8)     = make_ushort4(tmp[0], tmp[1], tmp[2], tmp[3]);
    *(ushort4*)(wb + t * 8 + 4) = make_ushort4(tmp[4], tmp[5], tmp[6], tmp[7]);
}

// Fused: blocks [0,nhb) do the bucket histogram (LDS-privatized), blocks
// [nhb,..) convert x fp32 -> bf16. Hist blocks first so their atomics overlap
// the convert stream.
__global__ __launch_bounds__(256) void conv_hist_kernel(
        const float4v* __restrict__ x4, ushort4v* __restrict__ xb4, int n4,
        const int* __restrict__ dst0, const int* __restrict__ dst1,
        int* __restrict__ ghist, int N, int E, int NB, int nhb) {
    if ((int)blockIdx.x < nhb) {
        __shared__ int h[NBMAX];
        int tid = threadIdx.x;
        for (int i = tid; i < NBMAX; i += 256) h[i] = 0;
        __syncthreads();
        int lo = blockIdx.x * CH2, hi = min(2 * E, lo + CH2);
        for (int i = lo + tid; i < hi; i += 256) {
            int r = (i >= E) ? 1 : 0;
            int e = i - r * E;
            int t = r ? dst1[e] : dst0[e];
            atomicAdd(&h[(r * N + t) >> 7], 1);
        }
        __syncthreads();
        for (int b = tid; b < NB; b += 256) {
            int c = h[b];
            if (c) atomicAdd(&ghist[b], c);
        }
    } else {
        int i = ((int)blockIdx.x - nhb) * 256 + threadIdx.x;
        if (i < n4) {
            float4v v = __builtin_nontemporal_load(x4 + i);
            ushort4v o;
            o[0] = __hip_bfloat16_raw(__float2bfloat16(v[0])).x;
            o[1] = __hip_bfloat16_raw(__float2bfloat16(v[1])).x;
            o[2] = __hip_bfloat16_raw(__float2bfloat16(v[2])).x;
            o[3] = __hip_bfloat16_raw(__float2bfloat16(v[3])).x;
            xb4[i] = o;
        }
    }
}

// Exclusive scan of ghist[n] -> S (+cursor copy); S[n] = total sentinel.
__global__ __launch_bounds__(256) void scan_kernel(const int* __restrict__ ghist,
                                                   int* __restrict__ S,
                                                   int* __restrict__ cursor,
                                                   int n, int total) {
    __shared__ int psum[256];
    int t = threadIdx.x;
    int cs = (n + 255) / 256;
    int s = 0;
    for (int j = 0; j < cs; ++j) {
        int idx = t * cs + j;
        if (idx < n) s += ghist[idx];
    }
    psum[t] = s; __syncthreads();
    for (int off = 1; off < 256; off <<= 1) {
        int add = (t >= off) ? psum[t - off] : 0;
        __syncthreads();
        psum[t] += add;
        __syncthreads();
    }
    int run = psum[t] - s;
    for (int j = 0; j < cs; ++j) {
        int idx = t * cs + j;
        if (idx < n) { S[idx] = run; cursor[idx] = run; run += ghist[idx]; }
    }
    if (t == 0) S[n] = total;
}

// Block-staged scatter: pass 1 local hist; bulk-reserve one run per
// (block,bucket); pass 2 re-read edges (L2-hot) and write into the run via
// LDS bump. Writes are contiguous ~10-edge runs -> low line amplification.
__global__ __launch_bounds__(256) void bin_kernel(
        const int* __restrict__ src0, const int* __restrict__ dst0,
        const int* __restrict__ src1, const int* __restrict__ dst1,
        int* __restrict__ cursor, unsigned* __restrict__ binned, int N, int E) {
    __shared__ int cnt[NBMAX];
    __shared__ int base[NBMAX];
    int tid = threadIdx.x;
    for (int i = tid; i < NBMAX; i += 256) cnt[i] = 0;
    __syncthreads();
    int lo = blockIdx.x * CH2, hi = min(2 * E, lo + CH2);
    for (int i = lo + tid; i < hi; i += 256) {
        int r = (i >= E) ? 1 : 0;
        int e = i - r * E;
        int t = r ? dst1[e] : dst0[e];
        atomicAdd(&cnt[(r * N + t) >> 7], 1);
    }
    __syncthreads();
    for (int b = tid; b < NBMAX; b += 256) {
        int c = cnt[b];
        if (c) base[b] = atomicAdd(&cursor[b], c);
    }
    __syncthreads();
    for (int i = lo + tid; i < hi; i += 256) {
        int r = (i >= E) ? 1 : 0;
        int e = i - r * E;
        int s = r ? src1[e] : src0[e];
        int t = r ? dst1[e] : dst0[e];
        int p = r * N + t;
        int slot = atomicAdd(&base[p >> 7], 1);
        binned[slot] = ((unsigned)(p & 127) << 17) | (unsigned)s;
    }
}

// One block per bucket (128 p's). Stage the bucket segment in LDS once (ebA),
// build the per-p CSR LDS->LDS (ebB), then one half-wave (32 lanes) per p with
// a depth-2 software-pipelined gather (8 row-gathers in flight).
__global__ __launch_bounds__(256) void agg_kernel(
        const uint2v* __restrict__ xb2,       // x bf16 rows as uint2v[N][32]
        const unsigned* __restrict__ binned,
        const int* __restrict__ S,
        unsigned short* __restrict__ aggb, int M) {
    __shared__ unsigned ebA[CAPN];
    __shared__ unsigned ebB[CAPN];
    __shared__ int cnt[128], cur[128], rs[128], sh[128];
    int tid = threadIdx.x;
    int b = blockIdx.x;
    int estart = S[b], eend = S[b + 1];
    int total = eend - estart;
    int P0 = b << 7;
    int hw = tid >> 5, lane = tid & 31;

    if (total <= CAPN) {
        if (tid < 128) cnt[tid] = 0;
        // single global pass over the (contiguous) bucket segment, nt so the
        // xb gather working set stays L2-resident
        for (int i = tid; i < total; i += 256)
            ebA[i] = __builtin_nontemporal_load(binned + estart + i);
        __syncthreads();
        for (int i = tid; i < total; i += 256)
            atomicAdd(&cnt[ebA[i] >> 17], 1);
        __syncthreads();
        if (tid < 128) sh[tid] = cnt[tid];
        __syncthreads();
        for (int off = 1; off < 128; off <<= 1) {
            int add = (tid < 128 && tid >= off) ? sh[tid - off] : 0;
            __syncthreads();
            if (tid < 128) sh[tid] += add;
            __syncthreads();
        }
        if (tid < 128) { rs[tid] = sh[tid] - cnt[tid]; cur[tid] = sh[tid] - cnt[tid]; }
        __syncthreads();
        for (int i = tid; i < total; i += 256) {
            unsigned v = ebA[i];
            int slot = atomicAdd(&cur[v >> 17], 1);
            ebB[slot] = v;
        }
        __syncthreads();

        for (int pi = 0; pi < 16; ++pi) {
            int pl = hw * 16 + pi;
            int s0 = rs[pl], c = cnt[pl];
            float4v a = (float4v){0.f, 0.f, 0.f, 0.f};
            int e = 0;
            if (c >= 4) {
                // prologue: load group 0
                int sA = ebB[s0]     & 0x1FFFF;
                int sB = ebB[s0 + 1] & 0x1FFFF;
                int sC = ebB[s0 + 2] & 0x1FFFF;
                int sD = ebB[s0 + 3] & 0x1FFFF;
                uint2v cAq = xb2[(size_t)sA * 32 + lane];
                uint2v cBq = xb2[(size_t)sB * 32 + lane];
                uint2v cCq = xb2[(size_t)sC * 32 + lane];
                uint2v cDq = xb2[(size_t)sD * 32 + lane];
                // steady state: issue group e, then consume group e-4
                for (e = 4; e + 4 <= c; e += 4) {
                    int nA = ebB[s0 + e]     & 0x1FFFF;
                    int nB = ebB[s0 + e + 1] & 0x1FFFF;
                    int nC = ebB[s0 + e + 2] & 0x1FFFF;
                    int nD = ebB[s0 + e + 3] & 0x1FFFF;
                    uint2v gA = xb2[(size_t)nA * 32 + lane];
                    uint2v gB = xb2[(size_t)nB * 32 + lane];
                    uint2v gC = xb2[(size_t)nC * 32 + lane];
                    uint2v gD = xb2[(size_t)nD * 32 + lane];
                    float4v t0 = bfexp(cAq) + bfexp(cBq);
                    float4v t1 = bfexp(cCq) + bfexp(cDq);
                    a += t0 + t1;
                    cAq = gA; cBq = gB; cCq = gC; cDq = gD;
                }
                // epilogue: consume last preloaded group
                float4v t0 = bfexp(cAq) + bfexp(cBq);
                float4v t1 = bfexp(cCq) + bfexp(cDq);
                a += t0 + t1;
            }
            for (; e < c; ++e) {
                int s = ebB[s0 + e] & 0x1FFFF;
                a += bfexp(xb2[(size_t)s * 32 + lane]);
            }
            int pg = P0 + pl;
            if (pg < M) {
                float inv = 1.0f / (float)max(c, 1);
                ushort4v w;
                w[0] = __hip_bfloat16_raw(__float2bfloat16(a[0] * inv)).x;
                w[1] = __hip_bfloat16_raw(__float2bfloat16(a[1] * inv)).x;
                w[2] = __hip_bfloat16_raw(__float2bfloat16(a[2] * inv)).x;
                w[3] = __hip_bfloat16_raw(__float2bfloat16(a[3] * inv)).x;
                __builtin_nontemporal_store(
                    w, (ushort4v*)(aggb + (size_t)pg * DFEAT + 4 * lane));
            }
        }
    } else {
        // overflow fallback (never triggers at these sizes): linear scan
        for (int pi = 0; pi < 16; ++pi) {
            int pl = hw * 16 + pi;
            float4v a = (float4v){0.f, 0.f, 0.f, 0.f};
            int c = 0;
            for (int i = estart; i < eend; ++i) {
                unsigned v = binned[i];
                if ((int)(v >> 17) == pl) {
                    ++c;
                    a += bfexp(xb2[(size_t)(v & 0x1FFFF) * 32 + lane]);
                }
            }
            int pg = P0 + pl;
            if (pg < M) {
                float inv = 1.0f / (float)max(c, 1);
                ushort4v w;
                w[0] = __hip_bfloat16_raw(__float2bfloat16(a[0] * inv)).x;
                w[1] = __hip_bfloat16_raw(__float2bfloat16(a[1] * inv)).x;
                w[2] = __hip_bfloat16_raw(__float2bfloat16(a[2] * inv)).x;
                w[3] = __hip_bfloat16_raw(__float2bfloat16(a[3] * inv)).x;
                *(ushort4v*)(aggb + (size_t)pg * DFEAT + 4 * lane) = w;
            }
        }
    }
}

// MFMA GEMM: out[row,col] = relu(sum_k A[row,k]*B[k,col] + bias[col]),
// A row = [aggb[row] | aggb[N+row] | xb[row]] (bf16), B pre-packed (wb).
__global__ __launch_bounds__(256) void mfma_gemm_kernel(
        const unsigned short* __restrict__ aggb,
        const unsigned short* __restrict__ xb,
        const unsigned short* __restrict__ wb,
        const float* __restrict__ bias,
        float* __restrict__ out, int N) {
    int tid = threadIdx.x;
    int wv = tid >> 6, lane = tid & 63;
    int R0 = blockIdx.x * 128 + wv * 32;
    int mrow = lane & 15, quad = lane >> 4;

    float4v acc[2][8];
#pragma unroll
    for (int rt = 0; rt < 2; ++rt)
#pragma unroll
        for (int ct = 0; ct < 8; ++ct) acc[rt][ct] = (float4v){0.f, 0.f, 0.f, 0.f};

    int n0 = min(R0 + mrow, N - 1);
    int n1 = min(R0 + 16 + mrow, N - 1);

#pragma unroll
    for (int kc = 0; kc < 12; ++kc) {
        int off = (kc & 3) * 32 + quad * 8;
        const unsigned short* s0;
        const unsigned short* s1;
        if (kc < 4)      { s0 = aggb + (size_t)n0 * DFEAT;       s1 = aggb + (size_t)n1 * DFEAT; }
        else if (kc < 8) { s0 = aggb + (size_t)(N + n0) * DFEAT; s1 = aggb + (size_t)(N + n1) * DFEAT; }
        else             { s0 = xb + (size_t)n0 * DFEAT;         s1 = xb + (size_t)n1 * DFEAT; }
        short8v a0 = *(const short8v*)(s0 + off);
        short8v a1 = *(const short8v*)(s1 + off);
#pragma unroll
        for (int ct = 0; ct < 8; ++ct) {
            short8v bfr = *(const short8v*)(wb + (((kc * 8 + ct) << 6) + lane) * 8);
            acc[0][ct] = __builtin_amdgcn_mfma_f32_16x16x32_bf16(a0, bfr, acc[0][ct], 0, 0, 0);
            acc[1][ct] = __builtin_amdgcn_mfma_f32_16x16x32_bf16(a1, bfr, acc[1][ct], 0, 0, 0);
        }
    }

#pragma unroll
    for (int ct = 0; ct < 8; ++ct) {
        int col = ct * 16 + mrow;
        float bv = bias[col];
#pragma unroll
        for (int rt = 0; rt < 2; ++rt) {
#pragma unroll
            for (int i = 0; i < 4; ++i) {
                int row = R0 + rt * 16 + quad * 4 + i;
                if (row < N)
                    __builtin_nontemporal_store(fmaxf(acc[rt][ct][i] + bv, 0.f),
                                                out + (size_t)row * DFEAT + col);
            }
        }
    }
}

extern "C" void kernel_launch(void* const* d_in, const int* in_sizes, int n_in,
                              void* d_out, int out_size, void* d_ws, size_t ws_size,
                              hipStream_t stream) {
    const float* x      = (const float*)d_in[0];
    const int* src_fwd  = (const int*)d_in[1];
    const int* dst_fwd  = (const int*)d_in[2];
    const int* src_bwd  = (const int*)d_in[3];
    const int* dst_bwd  = (const int*)d_in[4];
    const float* wrel   = (const float*)d_in[5];
    const float* wloop  = (const float*)d_in[6];
    const float* hbias  = (const float*)d_in[7];
    float* out          = (float*)d_out;

    int N = in_sizes[0] / DFEAT;
    int E = in_sizes[1];
    int M = 2 * N;
    int TE = 2 * E;
    int NB = (M + 127) / 128;        // 1563

    unsigned short* wb   = (unsigned short*)d_ws;                  // 96KB
    unsigned* binned     = (unsigned*)(wb + 12 * 8 * 64 * 8);      // [2E]
    unsigned short* xb   = (unsigned short*)(binned + (size_t)TE); // [N*128]
    unsigned short* aggb = xb + (size_t)N * DFEAT;                 // [2N*128]
    int* ghist           = (int*)(aggb + (size_t)M * DFEAT);       // [NB]
    int* S               = ghist + NB;                             // [NB+1]
    int* cursor          = S + NB + 1;                             // [NB]

    int n4 = N * (DFEAT / 4);
    int nconv = (n4 + 255) / 256;
    int nhb = (TE + CH2 - 1) / CH2;   // 196

    pack_b_kernel<<<24, 256, 0, stream>>>(wrel, wloop, wb, ghist, NB);

    conv_hist_kernel<<<nhb + nconv, 256, 0, stream>>>(
        (const float4v*)x, (ushort4v*)xb, n4, dst_fwd, dst_bwd, ghist, N, E, NB, nhb);

    scan_kernel<<<1, 256, 0, stream>>>(ghist, S, cursor, NB, TE);

    bin_kernel<<<nhb, 256, 0, stream>>>(
        src_fwd, dst_fwd, src_bwd, dst_bwd, cursor, binned, N, E);

    agg_kernel<<<NB, 256, 0, stream>>>((const uint2v*)xb, binned, S, aggb, M);

    mfma_gemm_kernel<<<(N + 127) / 128, 256, 0, stream>>>(
        aggb, xb, wb, hbias, out, N);
}

// Round 2
// 389.589 us; speedup vs baseline: 1.0353x; 1.0353x over previous
//
#include <hip/hip_runtime.h>
#include <hip/hip_bf16.h>

// R-GCN layer (fp32 in/out): out = relu(agg0/deg0 @ W0 + agg1/deg1 @ W1 + x @ Wl + b)
// Round 9: agg occupancy fix. Buckets shrunk 128->64 dst nodes (NB 1563->3125,
// 12.2 blocks/CU vs 6.1 -> grid actually fills the 8-block/CU thread limit),
// LDS back under 8KB (ebuf[1536]) so blocks/CU stays thread-limited, LDS
// double-buffer staging of round 8 dropped (it cost occupancy), 64-wide scan
// done with __shfl_up in wave 0 (no barrier ladder). Keeps round-8 launch
// fusions (pack_b+zero, conv+hist) and depth-2 pipelined gather.
//
// ws: wb ushort[12*8*64*8] | binned uint[2E] | xb bf16[N*128] |
//     aggb bf16[2N*128] | ghist int[NB] | S int[NB+1] | cursor int[NB]
// Requires N <= 131072 (src packed into 17 bits).

#define DFEAT 128
#define CH2 16384        // edges per hist/bin block
#define PSH 6            // bucket = 64 dst nodes
#define NBMAX 3200       // max buckets = ceil(2N/64)
#define CAPN 1536        // LDS edge capacity per bucket (mean 1024, sd ~32 -> +16 sigma)

typedef __attribute__((ext_vector_type(8))) short short8v;       // 8 bf16 (4 VGPRs)
typedef __attribute__((ext_vector_type(4))) float float4v;       // 4 fp32
typedef __attribute__((ext_vector_type(2))) unsigned int uint2v; // 8B
typedef __attribute__((ext_vector_type(4))) unsigned short ushort4v;

__device__ __forceinline__ float4v bfexp(uint2v g) {
    // unpack 4 bf16 (packed in 2 dwords) to 4 fp32
    float4v v;
    v[0] = __uint_as_float(g[0] << 16);
    v[1] = __uint_as_float(g[0] & 0xffff0000u);
    v[2] = __uint_as_float(g[1] << 16);
    v[3] = __uint_as_float(g[1] & 0xffff0000u);
    return v;
}

// Pack B[k][col] (k<256: wrel, else wloop) into MFMA B-fragment order; also
// zero ghist (6144 threads >= NB).
__global__ void pack_b_kernel(const float* __restrict__ wrel,
                              const float* __restrict__ wloop,
                              unsigned short* __restrict__ wb,
                              int* __restrict__ ghist, int NB) {
    int t = blockIdx.x * blockDim.x + threadIdx.x;   // 0..6143
    if (t < NB) ghist[t] = 0;
    if (t >= 12 * 8 * 64) return;
    int lane = t & 63;
    int kbase = (t >> 9) * 32 + (lane >> 4) * 8;
    int col = (((t >> 6) & 7) << 4) + (lane & 15);
    unsigned short tmp[8];
#pragma unroll
    for (int j = 0; j < 8; ++j) {
        int k = kbase + j;
        float v = (k < 256) ? wrel[k * DFEAT + col] : wloop[(k - 256) * DFEAT + col];
        tmp[j] = __hip_bfloat16_raw(__float2bfloat16(v)).x;
    }
    *(ushort4*)(wb + t * 8)     = make_ushort4(tmp[0], tmp[1], tmp[2], tmp[3]);
    *(ushort4*)(wb + t * 8 + 4) = make_ushort4(tmp[4], tmp[5], tmp[6], tmp[7]);
}

// Fused: blocks [0,nhb) do the bucket histogram (LDS-privatized), blocks
// [nhb,..) convert x fp32 -> bf16. Hist blocks first so their atomics overlap
// the convert stream.
__global__ __launch_bounds__(256) void conv_hist_kernel(
        const float4v* __restrict__ x4, ushort4v* __restrict__ xb4, int n4,
        const int* __restrict__ dst0, const int* __restrict__ dst1,
        int* __restrict__ ghist, int N, int E, int NB, int nhb) {
    if ((int)blockIdx.x < nhb) {
        __shared__ int h[NBMAX];
        int tid = threadIdx.x;
        for (int i = tid; i < NBMAX; i += 256) h[i] = 0;
        __syncthreads();
        int lo = blockIdx.x * CH2, hi = min(2 * E, lo + CH2);
        for (int i = lo + tid; i < hi; i += 256) {
            int r = (i >= E) ? 1 : 0;
            int e = i - r * E;
            int t = r ? dst1[e] : dst0[e];
            atomicAdd(&h[(r * N + t) >> PSH], 1);
        }
        __syncthreads();
        for (int b = tid; b < NB; b += 256) {
            int c = h[b];
            if (c) atomicAdd(&ghist[b], c);
        }
    } else {
        int i = ((int)blockIdx.x - nhb) * 256 + threadIdx.x;
        if (i < n4) {
            float4v v = __builtin_nontemporal_load(x4 + i);
            ushort4v o;
            o[0] = __hip_bfloat16_raw(__float2bfloat16(v[0])).x;
            o[1] = __hip_bfloat16_raw(__float2bfloat16(v[1])).x;
            o[2] = __hip_bfloat16_raw(__float2bfloat16(v[2])).x;
            o[3] = __hip_bfloat16_raw(__float2bfloat16(v[3])).x;
            xb4[i] = o;
        }
    }
}

// Exclusive scan of ghist[n] -> S (+cursor copy); S[n] = total sentinel.
__global__ __launch_bounds__(256) void scan_kernel(const int* __restrict__ ghist,
                                                   int* __restrict__ S,
                                                   int* __restrict__ cursor,
                                                   int n, int total) {
    __shared__ int psum[256];
    int t = threadIdx.x;
    int cs = (n + 255) / 256;
    int s = 0;
    for (int j = 0; j < cs; ++j) {
        int idx = t * cs + j;
        if (idx < n) s += ghist[idx];
    }
    psum[t] = s; __syncthreads();
    for (int off = 1; off < 256; off <<= 1) {
        int add = (t >= off) ? psum[t - off] : 0;
        __syncthreads();
        psum[t] += add;
        __syncthreads();
    }
    int run = psum[t] - s;
    for (int j = 0; j < cs; ++j) {
        int idx = t * cs + j;
        if (idx < n) { S[idx] = run; cursor[idx] = run; run += ghist[idx]; }
    }
    if (t == 0) S[n] = total;
}

// Block-staged scatter: pass 1 local hist; bulk-reserve one run per
// (block,bucket); pass 2 re-read edges (L2-hot) and write into the run via
// LDS bump. Writes are contiguous runs -> low line amplification.
__global__ __launch_bounds__(256) void bin_kernel(
        const int* __restrict__ src0, const int* __restrict__ dst0,
        const int* __restrict__ src1, const int* __restrict__ dst1,
        int* __restrict__ cursor, unsigned* __restrict__ binned, int N, int E) {
    __shared__ int cnt[NBMAX];
    __shared__ int base[NBMAX];
    int tid = threadIdx.x;
    for (int i = tid; i < NBMAX; i += 256) cnt[i] = 0;
    __syncthreads();
    int lo = blockIdx.x * CH2, hi = min(2 * E, lo + CH2);
    for (int i = lo + tid; i < hi; i += 256) {
        int r = (i >= E) ? 1 : 0;
        int e = i - r * E;
        int t = r ? dst1[e] : dst0[e];
        atomicAdd(&cnt[(r * N + t) >> PSH], 1);
    }
    __syncthreads();
    for (int b = tid; b < NBMAX; b += 256) {
        int c = cnt[b];
        if (c) base[b] = atomicAdd(&cursor[b], c);
    }
    __syncthreads();
    for (int i = lo + tid; i < hi; i += 256) {
        int r = (i >= E) ? 1 : 0;
        int e = i - r * E;
        int s = r ? src1[e] : src0[e];
        int t = r ? dst1[e] : dst0[e];
        int p = r * N + t;
        int slot = atomicAdd(&base[p >> PSH], 1);
        binned[slot] = ((unsigned)(p & 63) << 17) | (unsigned)s;
    }
}

// One block per bucket (64 p's). Two L2-hot global passes over the bucket
// segment (hist, then counting-scatter into LDS ebuf), 64-lane shfl scan in
// wave 0, then one half-wave (32 lanes) per p with a depth-2 software-
// pipelined gather (8 row-gathers in flight).
__global__ __launch_bounds__(256) void agg_kernel(
        const uint2v* __restrict__ xb2,       // x bf16 rows as uint2v[N][32]
        const unsigned* __restrict__ binned,
        const int* __restrict__ S,
        unsigned short* __restrict__ aggb, int M) {
    __shared__ unsigned ebuf[CAPN];
    __shared__ int cnt[64], cur[64], rs[64];
    int tid = threadIdx.x;
    int b = blockIdx.x;
    int estart = S[b], eend = S[b + 1];
    int total = eend - estart;
    int P0 = b << PSH;
    int hw = tid >> 5, lane = tid & 31;

    if (total <= CAPN) {
        if (tid < 64) cnt[tid] = 0;
        __syncthreads();
        for (int i = estart + tid; i < eend; i += 256)
            atomicAdd(&cnt[binned[i] >> 17], 1);
        __syncthreads();
        if (tid < 64) {
            int v = cnt[tid];
            int inc = v;
#pragma unroll
            for (int off = 1; off < 64; off <<= 1) {
                int t2 = __shfl_up(inc, off);
                if (tid >= off) inc += t2;
            }
            rs[tid] = inc - v;
            cur[tid] = inc - v;
        }
        __syncthreads();
        for (int i = estart + tid; i < eend; i += 256) {
            unsigned v = binned[i];
            int slot = atomicAdd(&cur[v >> 17], 1);
            ebuf[slot] = v;
        }
        __syncthreads();

        for (int pi = 0; pi < 8; ++pi) {
            int pl = hw * 8 + pi;
            int s0 = rs[pl], c = cnt[pl];
            float4v a = (float4v){0.f, 0.f, 0.f, 0.f};
            int e = 0;
            if (c >= 4) {
                // prologue: load group 0
                int sA = ebuf[s0]     & 0x1FFFF;
                int sB = ebuf[s0 + 1] & 0x1FFFF;
                int sC = ebuf[s0 + 2] & 0x1FFFF;
                int sD = ebuf[s0 + 3] & 0x1FFFF;
                uint2v cAq = xb2[(size_t)sA * 32 + lane];
                uint2v cBq = xb2[(size_t)sB * 32 + lane];
                uint2v cCq = xb2[(size_t)sC * 32 + lane];
                uint2v cDq = xb2[(size_t)sD * 32 + lane];
                // steady state: issue group e, then consume group e-4
                for (e = 4; e + 4 <= c; e += 4) {
                    int nA = ebuf[s0 + e]     & 0x1FFFF;
                    int nB = ebuf[s0 + e + 1] & 0x1FFFF;
                    int nC = ebuf[s0 + e + 2] & 0x1FFFF;
                    int nD = ebuf[s0 + e + 3] & 0x1FFFF;
                    uint2v gA = xb2[(size_t)nA * 32 + lane];
                    uint2v gB = xb2[(size_t)nB * 32 + lane];
                    uint2v gC = xb2[(size_t)nC * 32 + lane];
                    uint2v gD = xb2[(size_t)nD * 32 + lane];
                    float4v t0 = bfexp(cAq) + bfexp(cBq);
                    float4v t1 = bfexp(cCq) + bfexp(cDq);
                    a += t0 + t1;
                    cAq = gA; cBq = gB; cCq = gC; cDq = gD;
                }
                // epilogue: consume last preloaded group
                float4v t0 = bfexp(cAq) + bfexp(cBq);
                float4v t1 = bfexp(cCq) + bfexp(cDq);
                a += t0 + t1;
            }
            for (; e < c; ++e) {
                int s = ebuf[s0 + e] & 0x1FFFF;
                a += bfexp(xb2[(size_t)s * 32 + lane]);
            }
            int pg = P0 + pl;
            if (pg < M) {
                float inv = 1.0f / (float)max(c, 1);
                ushort4v w;
                w[0] = __hip_bfloat16_raw(__float2bfloat16(a[0] * inv)).x;
                w[1] = __hip_bfloat16_raw(__float2bfloat16(a[1] * inv)).x;
                w[2] = __hip_bfloat16_raw(__float2bfloat16(a[2] * inv)).x;
                w[3] = __hip_bfloat16_raw(__float2bfloat16(a[3] * inv)).x;
                __builtin_nontemporal_store(
                    w, (ushort4v*)(aggb + (size_t)pg * DFEAT + 4 * lane));
            }
        }
    } else {
        // overflow fallback (never triggers at these sizes): linear scan
        for (int pi = 0; pi < 8; ++pi) {
            int pl = hw * 8 + pi;
            float4v a = (float4v){0.f, 0.f, 0.f, 0.f};
            int c = 0;
            for (int i = estart; i < eend; ++i) {
                unsigned v = binned[i];
                if ((int)(v >> 17) == pl) {
                    ++c;
                    a += bfexp(xb2[(size_t)(v & 0x1FFFF) * 32 + lane]);
                }
            }
            int pg = P0 + pl;
            if (pg < M) {
                float inv = 1.0f / (float)max(c, 1);
                ushort4v w;
                w[0] = __hip_bfloat16_raw(__float2bfloat16(a[0] * inv)).x;
                w[1] = __hip_bfloat16_raw(__float2bfloat16(a[1] * inv)).x;
                w[2] = __hip_bfloat16_raw(__float2bfloat16(a[2] * inv)).x;
                w[3] = __hip_bfloat16_raw(__float2bfloat16(a[3] * inv)).x;
                *(ushort4v*)(aggb + (size_t)pg * DFEAT + 4 * lane) = w;
            }
        }
    }
}

// MFMA GEMM: out[row,col] = relu(sum_k A[row,k]*B[k,col] + bias[col]),
// A row = [aggb[row] | aggb[N+row] | xb[row]] (bf16), B pre-packed (wb).
__global__ __launch_bounds__(256) void mfma_gemm_kernel(
        const unsigned short* __restrict__ aggb,
        const unsigned short* __restrict__ xb,
        const unsigned short* __restrict__ wb,
        const float* __restrict__ bias,
        float* __restrict__ out, int N) {
    int tid = threadIdx.x;
    int wv = tid >> 6, lane = tid & 63;
    int R0 = blockIdx.x * 128 + wv * 32;
    int mrow = lane & 15, quad = lane >> 4;

    float4v acc[2][8];
#pragma unroll
    for (int rt = 0; rt < 2; ++rt)
#pragma unroll
        for (int ct = 0; ct < 8; ++ct) acc[rt][ct] = (float4v){0.f, 0.f, 0.f, 0.f};

    int n0 = min(R0 + mrow, N - 1);
    int n1 = min(R0 + 16 + mrow, N - 1);

#pragma unroll
    for (int kc = 0; kc < 12; ++kc) {
        int off = (kc & 3) * 32 + quad * 8;
        const unsigned short* s0;
        const unsigned short* s1;
        if (kc < 4)      { s0 = aggb + (size_t)n0 * DFEAT;       s1 = aggb + (size_t)n1 * DFEAT; }
        else if (kc < 8) { s0 = aggb + (size_t)(N + n0) * DFEAT; s1 = aggb + (size_t)(N + n1) * DFEAT; }
        else             { s0 = xb + (size_t)n0 * DFEAT;         s1 = xb + (size_t)n1 * DFEAT; }
        short8v a0 = *(const short8v*)(s0 + off);
        short8v a1 = *(const short8v*)(s1 + off);
#pragma unroll
        for (int ct = 0; ct < 8; ++ct) {
            short8v bfr = *(const short8v*)(wb + (((kc * 8 + ct) << 6) + lane) * 8);
            acc[0][ct] = __builtin_amdgcn_mfma_f32_16x16x32_bf16(a0, bfr, acc[0][ct], 0, 0, 0);
            acc[1][ct] = __builtin_amdgcn_mfma_f32_16x16x32_bf16(a1, bfr, acc[1][ct], 0, 0, 0);
        }
    }

#pragma unroll
    for (int ct = 0; ct < 8; ++ct) {
        int col = ct * 16 + mrow;
        float bv = bias[col];
#pragma unroll
        for (int rt = 0; rt < 2; ++rt) {
#pragma unroll
            for (int i = 0; i < 4; ++i) {
                int row = R0 + rt * 16 + quad * 4 + i;
                if (row < N)
                    __builtin_nontemporal_store(fmaxf(acc[rt][ct][i] + bv, 0.f),
                                                out + (size_t)row * DFEAT + col);
            }
        }
    }
}

extern "C" void kernel_launch(void* const* d_in, const int* in_sizes, int n_in,
                              void* d_out, int out_size, void* d_ws, size_t ws_size,
                              hipStream_t stream) {
    const float* x      = (const float*)d_in[0];
    const int* src_fwd  = (const int*)d_in[1];
    const int* dst_fwd  = (const int*)d_in[2];
    const int* src_bwd  = (const int*)d_in[3];
    const int* dst_bwd  = (const int*)d_in[4];
    const float* wrel   = (const float*)d_in[5];
    const float* wloop  = (const float*)d_in[6];
    const float* hbias  = (const float*)d_in[7];
    float* out          = (float*)d_out;

    int N = in_sizes[0] / DFEAT;
    int E = in_sizes[1];
    int M = 2 * N;
    int TE = 2 * E;
    int NB = (M + 63) / 64;          // 3125

    unsigned short* wb   = (unsigned short*)d_ws;                  // 96KB
    unsigned* binned     = (unsigned*)(wb + 12 * 8 * 64 * 8);      // [2E]
    unsigned short* xb   = (unsigned short*)(binned + (size_t)TE); // [N*128]
    unsigned short* aggb = xb + (size_t)N * DFEAT;                 // [2N*128]
    int* ghist           = (int*)(aggb + (size_t)M * DFEAT);       // [NB]
    int* S               = ghist + NB;                             // [NB+1]
    int* cursor          = S + NB + 1;                             // [NB]

    int n4 = N * (DFEAT / 4);
    int nconv = (n4 + 255) / 256;
    int nhb = (TE + CH2 - 1) / CH2;   // 196

    pack_b_kernel<<<24, 256, 0, stream>>>(wrel, wloop, wb, ghist, NB);

    conv_hist_kernel<<<nhb + nconv, 256, 0, stream>>>(
        (const float4v*)x, (ushort4v*)xb, n4, dst_fwd, dst_bwd, ghist, N, E, NB, nhb);

    scan_kernel<<<1, 256, 0, stream>>>(ghist, S, cursor, NB, TE);

    bin_kernel<<<nhb, 256, 0, stream>>>(
        src_fwd, dst_fwd, src_bwd, dst_bwd, cursor, binned, N, E);

    agg_kernel<<<NB, 256, 0, stream>>>((const uint2v*)xb, binned, S, aggb, M);

    mfma_gemm_kernel<<<(N + 127) / 128, 256, 0, stream>>>(
        aggb, xb, wb, hbias, out, N);
}

// Round 3
// 378.439 us; speedup vs baseline: 1.0658x; 1.0295x over previous
//
#include <hip/hip_runtime.h>
#include <hip/hip_bf16.h>

// R-GCN layer (fp32 in/out): out = relu(agg0/deg0 @ W0 + agg1/deg1 @ W1 + x @ Wl + b)
// Round 10:
//  (a) agg gather rewritten: full-wave dwordx4 loads (4 rows per load instr,
//      16 lanes x 16B per row), rolling depth-3 pipeline -> ~1 latency stall
//      per p instead of per 4-edge group; sentinel-padded runs (src=N -> zero
//      row) remove tails and divergence. One wave owns one p.
//  (b) pipeline shortened: fixed per-bucket regions in binned (CAPB=1536,
//      +16 sigma over Poisson(1024)) kill the global hist + scan; cursor
//      zeroed by hipMemsetAsync; pack_b/convert/bin fused into one front
//      kernel. 6 launches -> 4.
//
// ws: wb ushort[12*8*64*8] | binned uint[NB*CAPB] | xb bf16[(N+1)*128] |
//     aggb bf16[2N*128] | cursor int[NB]
// Requires N <= 131072 (src packed into 17 bits).

#define DFEAT 128
#define CH2 16384        // edges per bin block
#define PSH 6            // bucket = 64 dst nodes
#define NBMAX 3200       // max buckets = ceil(2N/64)
#define CAPB 1536        // fixed binned capacity per bucket (mean 1024, +16 sigma)
#define CAPP 1792        // LDS capacity: CAPB + 3*64 pad, rounded up
#define NPACK 24         // pack_b blocks

typedef __attribute__((ext_vector_type(8))) short short8v;       // 8 bf16 (4 VGPRs)
typedef __attribute__((ext_vector_type(4))) float float4v;       // 4 fp32
typedef __attribute__((ext_vector_type(4))) unsigned int uint4v; // 16B
typedef __attribute__((ext_vector_type(4))) unsigned short ushort4v;

// Fused front: blocks [0,nbin) bin edges into fixed bucket regions,
// [nbin,nbin+NPACK) pack W into MFMA B-fragment order, rest convert x->bf16
// (+ zero sentinel row N). All three sections are mutually independent.
__global__ __launch_bounds__(256) void front_kernel(
        const float4v* __restrict__ x4, ushort4v* __restrict__ xb4, int n4,
        const int* __restrict__ src0, const int* __restrict__ dst0,
        const int* __restrict__ src1, const int* __restrict__ dst1,
        int* __restrict__ cursor, unsigned* __restrict__ binned,
        const float* __restrict__ wrel, const float* __restrict__ wloop,
        unsigned short* __restrict__ wb,
        int N, int E, int nbin) {
    __shared__ int cnt[NBMAX];
    __shared__ int base[NBMAX];
    int tid = threadIdx.x;
    int bid = blockIdx.x;

    if (bid < nbin) {
        // ---- bin section: block-staged counting scatter ----
        for (int i = tid; i < NBMAX; i += 256) cnt[i] = 0;
        __syncthreads();
        int lo = bid * CH2, hi = min(2 * E, lo + CH2);
        // pass 1: local histogram
        for (int i = lo + tid; i < hi; i += 256) {
            int r = (i >= E) ? 1 : 0;
            int e = i - r * E;
            int t = r ? dst1[e] : dst0[e];
            atomicAdd(&cnt[(r * N + t) >> PSH], 1);
        }
        __syncthreads();
        // bulk-reserve one contiguous run per (block,bucket); absolute base
        for (int b = tid; b < NBMAX; b += 256) {
            int c = cnt[b];
            if (c) base[b] = b * CAPB + atomicAdd(&cursor[b], c);
        }
        __syncthreads();
        // pass 2: scatter into runs (edge reads L2-hot from pass 1)
        for (int i = lo + tid; i < hi; i += 256) {
            int r = (i >= E) ? 1 : 0;
            int e = i - r * E;
            int s = r ? src1[e] : src0[e];
            int t = r ? dst1[e] : dst0[e];
            int p = r * N + t;
            int slot = atomicAdd(&base[p >> PSH], 1);
            binned[slot] = ((unsigned)(p & 63) << 17) | (unsigned)s;
        }
    } else if (bid < nbin + NPACK) {
        // ---- pack_b section ----
        int t = (bid - nbin) * 256 + tid;    // 0..6143
        if (t < 12 * 8 * 64) {
            int lane = t & 63;
            int kbase = (t >> 9) * 32 + (lane >> 4) * 8;
            int col = (((t >> 6) & 7) << 4) + (lane & 15);
            unsigned short tmp[8];
#pragma unroll
            for (int j = 0; j < 8; ++j) {
                int k = kbase + j;
                float v = (k < 256) ? wrel[k * DFEAT + col]
                                    : wloop[(k - 256) * DFEAT + col];
                tmp[j] = __hip_bfloat16_raw(__float2bfloat16(v)).x;
            }
            *(ushort4*)(wb + t * 8)     = make_ushort4(tmp[0], tmp[1], tmp[2], tmp[3]);
            *(ushort4*)(wb + t * 8 + 4) = make_ushort4(tmp[4], tmp[5], tmp[6], tmp[7]);
        }
    } else {
        // ---- convert section ----
        int cb = bid - nbin - NPACK;
        int i = cb * 256 + tid;
        if (i < n4) {
            float4v v = __builtin_nontemporal_load(x4 + i);
            ushort4v o;
            o[0] = __hip_bfloat16_raw(__float2bfloat16(v[0])).x;
            o[1] = __hip_bfloat16_raw(__float2bfloat16(v[1])).x;
            o[2] = __hip_bfloat16_raw(__float2bfloat16(v[2])).x;
            o[3] = __hip_bfloat16_raw(__float2bfloat16(v[3])).x;
            xb4[i] = o;
        }
        if (cb == 0 && tid < 32) {
            // zero sentinel row N (gather target for pad edges)
            ushort4v z = (ushort4v){0, 0, 0, 0};
            xb4[n4 + tid] = z;
        }
    }
}

// One block per bucket (64 p's). LDS CSR with sentinel-padded runs (multiple
// of 4 edges per p). Gather: one wave per p, full-wave dwordx4 loads cover 4
// rows/instr (quarter-wave per row, 16B per lane), rolling depth-3 pipeline.
__global__ __launch_bounds__(256) void agg_kernel(
        const unsigned short* __restrict__ xb,
        const unsigned* __restrict__ binned,
        const int* __restrict__ cursor,
        unsigned short* __restrict__ aggb, int N, int M) {
    __shared__ unsigned ebuf[CAPP];
    __shared__ int cnt[64], cur[64], rs[64];
    int tid = threadIdx.x;
    int b = blockIdx.x;
    int total = min(cursor[b], CAPB);
    const unsigned* seg = binned + (size_t)b * CAPB;
    int P0 = b << PSH;
    unsigned SENT = (unsigned)N << 8;    // byte offset of zero row

    if (tid < 64) cnt[tid] = 0;
    for (int i = tid; i < CAPP; i += 256) ebuf[i] = SENT;
    __syncthreads();
    for (int i = tid; i < total; i += 256)
        atomicAdd(&cnt[seg[i] >> 17], 1);
    __syncthreads();
    if (tid < 64) {
        int c = cnt[tid];
        int cp = (c + 3) & ~3;           // padded run length
        int inc = cp;
#pragma unroll
        for (int off = 1; off < 64; off <<= 1) {
            int t2 = __shfl_up(inc, off);
            if (tid >= off) inc += t2;
        }
        rs[tid] = inc - cp;
        cur[tid] = inc - cp;
    }
    __syncthreads();
    for (int i = tid; i < total; i += 256) {
        unsigned v = seg[i];
        int slot = atomicAdd(&cur[v >> 17], 1);
        ebuf[slot] = (v & 0x1FFFF) << 8;  // pre-scaled byte offset of row
    }
    __syncthreads();

    int wv = tid >> 6, lane = tid & 63;
    int lq = lane >> 4;                  // quarter 0..3 -> edge within group
    int lb = (lane & 15) << 4;           // byte within row (16B per lane)
    const char* xbB = (const char*)xb;

#define ACCUM(Q) {                                          \
        A0[0] += __uint_as_float(Q[0] << 16);               \
        A0[1] += __uint_as_float(Q[0] & 0xffff0000u);       \
        A0[2] += __uint_as_float(Q[1] << 16);               \
        A0[3] += __uint_as_float(Q[1] & 0xffff0000u);       \
        A1[0] += __uint_as_float(Q[2] << 16);               \
        A1[1] += __uint_as_float(Q[2] & 0xffff0000u);       \
        A1[2] += __uint_as_float(Q[3] << 16);               \
        A1[3] += __uint_as_float(Q[3] & 0xffff0000u); }

    for (int pi = 0; pi < 16; ++pi) {
        int pl = wv * 16 + pi;
        int s0 = rs[pl], c = cnt[pl];
        int ng = (c + 3) >> 2;           // 4-edge groups (sentinel-padded)
        float4v A0 = (float4v){0.f, 0.f, 0.f, 0.f};
        float4v A1 = (float4v){0.f, 0.f, 0.f, 0.f};
        if (ng > 0) {
            uint4v c0, c1, nx;
            { unsigned off = ebuf[s0 + lq];
              c0 = *(const uint4v*)(xbB + off + lb); }
            if (ng > 1) {
                unsigned off = ebuf[s0 + 4 + lq];
                c1 = *(const uint4v*)(xbB + off + lb);
            }
            for (int g = 2; g < ng; ++g) {
                { unsigned off = ebuf[s0 + 4 * g + lq];
                  nx = *(const uint4v*)(xbB + off + lb); }
                ACCUM(c0);
                c0 = c1; c1 = nx;
            }
            ACCUM(c0);
            if (ng > 1) ACCUM(c1);
        }
        // reduce across the 4 quarters (same features, different edges)
#pragma unroll
        for (int j = 0; j < 4; ++j) {
            A0[j] += __shfl_xor(A0[j], 16);
            A0[j] += __shfl_xor(A0[j], 32);
            A1[j] += __shfl_xor(A1[j], 16);
            A1[j] += __shfl_xor(A1[j], 32);
        }
        int pg = P0 + pl;
        if (pg < M && lane < 16) {
            float inv = 1.0f / (float)max(c, 1);
            ushort4v w0, w1;
            w0[0] = __hip_bfloat16_raw(__float2bfloat16(A0[0] * inv)).x;
            w0[1] = __hip_bfloat16_raw(__float2bfloat16(A0[1] * inv)).x;
            w0[2] = __hip_bfloat16_raw(__float2bfloat16(A0[2] * inv)).x;
            w0[3] = __hip_bfloat16_raw(__float2bfloat16(A0[3] * inv)).x;
            w1[0] = __hip_bfloat16_raw(__float2bfloat16(A1[0] * inv)).x;
            w1[1] = __hip_bfloat16_raw(__float2bfloat16(A1[1] * inv)).x;
            w1[2] = __hip_bfloat16_raw(__float2bfloat16(A1[2] * inv)).x;
            w1[3] = __hip_bfloat16_raw(__float2bfloat16(A1[3] * inv)).x;
            unsigned short* dst = aggb + (size_t)pg * DFEAT + lane * 8;
            __builtin_nontemporal_store(w0, (ushort4v*)dst);
            __builtin_nontemporal_store(w1, (ushort4v*)(dst + 4));
        }
    }
#undef ACCUM
}

// MFMA GEMM: out[row,col] = relu(sum_k A[row,k]*B[k,col] + bias[col]),
// A row = [aggb[row] | aggb[N+row] | xb[row]] (bf16), B pre-packed (wb).
__global__ __launch_bounds__(256) void mfma_gemm_kernel(
        const unsigned short* __restrict__ aggb,
        const unsigned short* __restrict__ xb,
        const unsigned short* __restrict__ wb,
        const float* __restrict__ bias,
        float* __restrict__ out, int N) {
    int tid = threadIdx.x;
    int wv = tid >> 6, lane = tid & 63;
    int R0 = blockIdx.x * 128 + wv * 32;
    int mrow = lane & 15, quad = lane >> 4;

    float4v acc[2][8];
#pragma unroll
    for (int rt = 0; rt < 2; ++rt)
#pragma unroll
        for (int ct = 0; ct < 8; ++ct) acc[rt][ct] = (float4v){0.f, 0.f, 0.f, 0.f};

    int n0 = min(R0 + mrow, N - 1);
    int n1 = min(R0 + 16 + mrow, N - 1);

#pragma unroll
    for (int kc = 0; kc < 12; ++kc) {
        int off = (kc & 3) * 32 + quad * 8;
        const unsigned short* s0;
        const unsigned short* s1;
        if (kc < 4)      { s0 = aggb + (size_t)n0 * DFEAT;       s1 = aggb + (size_t)n1 * DFEAT; }
        else if (kc < 8) { s0 = aggb + (size_t)(N + n0) * DFEAT; s1 = aggb + (size_t)(N + n1) * DFEAT; }
        else             { s0 = xb + (size_t)n0 * DFEAT;         s1 = xb + (size_t)n1 * DFEAT; }
        short8v a0 = *(const short8v*)(s0 + off);
        short8v a1 = *(const short8v*)(s1 + off);
#pragma unroll
        for (int ct = 0; ct < 8; ++ct) {
            short8v bfr = *(const short8v*)(wb + (((kc * 8 + ct) << 6) + lane) * 8);
            acc[0][ct] = __builtin_amdgcn_mfma_f32_16x16x32_bf16(a0, bfr, acc[0][ct], 0, 0, 0);
            acc[1][ct] = __builtin_amdgcn_mfma_f32_16x16x32_bf16(a1, bfr, acc[1][ct], 0, 0, 0);
        }
    }

#pragma unroll
    for (int ct = 0; ct < 8; ++ct) {
        int col = ct * 16 + mrow;
        float bv = bias[col];
#pragma unroll
        for (int rt = 0; rt < 2; ++rt) {
#pragma unroll
            for (int i = 0; i < 4; ++i) {
                int row = R0 + rt * 16 + quad * 4 + i;
                if (row < N)
                    __builtin_nontemporal_store(fmaxf(acc[rt][ct][i] + bv, 0.f),
                                                out + (size_t)row * DFEAT + col);
            }
        }
    }
}

extern "C" void kernel_launch(void* const* d_in, const int* in_sizes, int n_in,
                              void* d_out, int out_size, void* d_ws, size_t ws_size,
                              hipStream_t stream) {
    const float* x      = (const float*)d_in[0];
    const int* src_fwd  = (const int*)d_in[1];
    const int* dst_fwd  = (const int*)d_in[2];
    const int* src_bwd  = (const int*)d_in[3];
    const int* dst_bwd  = (const int*)d_in[4];
    const float* wrel   = (const float*)d_in[5];
    const float* wloop  = (const float*)d_in[6];
    const float* hbias  = (const float*)d_in[7];
    float* out          = (float*)d_out;

    int N = in_sizes[0] / DFEAT;
    int E = in_sizes[1];
    int M = 2 * N;
    int TE = 2 * E;
    int NB = (M + 63) / 64;          // 3125

    unsigned short* wb   = (unsigned short*)d_ws;                        // 96KB
    unsigned* binned     = (unsigned*)(wb + 12 * 8 * 64 * 8);            // [NB*CAPB]
    unsigned short* xb   = (unsigned short*)(binned + (size_t)NB * CAPB);// [(N+1)*128]
    unsigned short* aggb = xb + (size_t)(N + 1) * DFEAT;                 // [2N*128]
    int* cursor          = (int*)(aggb + (size_t)M * DFEAT);             // [NB]

    int n4 = N * (DFEAT / 4);
    int nconv = (n4 + 255) / 256;
    int nbin = (TE + CH2 - 1) / CH2;   // 196

    hipMemsetAsync(cursor, 0, NB * sizeof(int), stream);

    front_kernel<<<nbin + NPACK + nconv, 256, 0, stream>>>(
        (const float4v*)x, (ushort4v*)xb, n4,
        src_fwd, dst_fwd, src_bwd, dst_bwd,
        cursor, binned, wrel, wloop, wb, N, E, nbin);

    agg_kernel<<<NB, 256, 0, stream>>>(xb, binned, cursor, aggb, N, M);

    mfma_gemm_kernel<<<(N + 127) / 128, 256, 0, stream>>>(
        aggb, xb, wb, hbias, out, N);
}